// Round 7
// baseline (277.579 us; speedup 1.0000x reference)
//
#include <hip/hip_runtime.h>

typedef unsigned short u16;
typedef u16 u16x8 __attribute__((ext_vector_type(8)));
typedef __bf16 bf16x8 __attribute__((ext_vector_type(8)));
typedef float f32x4 __attribute__((ext_vector_type(4)));

#define HB   256    // H
#define NND  127    // nodes per tree
#define BT   512    // trees (batch)
#define KE   300    // E
#define KEP  320    // E padded to 32-multiple
#define VV   50000  // vocab
#define QQ   10     // Q

#define AS1 __attribute__((address_space(1)))
#define AS3 __attribute__((address_space(3)))

__device__ __forceinline__ u16 f2bf(float f) {
    unsigned int u = __builtin_bit_cast(unsigned int, f);
    u += 0x7FFFu + ((u >> 16) & 1u);          // RNE
    return (u16)(u >> 16);
}
__device__ __forceinline__ float bf2f(u16 h) {
    unsigned int u = ((unsigned int)h) << 16;
    return __builtin_bit_cast(float, u);
}
__device__ __forceinline__ float sigm(float x) { return 1.f / (1.f + __expf(-x)); }

__device__ __forceinline__ void glds16(const u16* g, u16* l) {
    __builtin_amdgcn_global_load_lds((const AS1 void*)g, (AS3 void*)l, 16, 0, 0);
}

// ---------- fp32 -> bf16 convert with K -> Kp zero padding, u16x8 stores ----------
__global__ __launch_bounds__(256) void k_conv(const float* __restrict__ src,
                                              u16* __restrict__ dst,
                                              int rows, int K, int Kp) {
    int i = blockIdx.x * 256 + threadIdx.x;   // one 8-elem chunk per thread
    int nch = Kp >> 3;
    if (i >= rows * nch) return;
    int r = i / nch, c = (i - r * nch) * 8;
    const float* s = src + (long)r * K + c;
    u16x8 o;
#pragma unroll
    for (int e = 0; e < 8; ++e) o[e] = (c + e < K) ? f2bf(s[e]) : (u16)0;
    *(u16x8*)(dst + (long)i * 8) = o;
}

// ---------- qD = q @ D.T  (QQ x 768), fp32 ----------
__global__ __launch_bounds__(256) void k_qd(const float* __restrict__ q,
                                            const float* __restrict__ D,
                                            float* __restrict__ qD) {
    int i = blockIdx.x * 256 + threadIdx.x;
    if (i >= QQ * 768) return;
    int qi = i / 768, col = i - qi * 768;
    const float* qr = q + qi * HB;
    const float* dr = D + col * HB;
    float s = 0.f;
    for (int k = 0; k < HB; ++k) s += qr[k] * dr[k];
    qD[i] = s;
}

// ---------- bf16 NT GEMM: 256x256 tile, 512 thr / 8 waves (2Mx4N), glds(16B), 2-phase ----------
// C[M,N] = A[M,K] * B[N,K]^T ; A,B bf16 row-major, K % 64 == 0 (nk even), N % 256 == 0.
// optional A-row map: global_row = (r>>cnlog2)*127 + cstart + (r & ((1<<cnlog2)-1))
template <bool STORE_BF16>
__global__ __launch_bounds__(512, 2) void k_gemm(const u16* __restrict__ A,
                                                 const u16* __restrict__ B,
                                                 void* __restrict__ C,
                                                 int M, int N, int K,
                                                 int map_cnlog2, int map_cstart) {
    __shared__ u16 As[2][256 * 32];
    __shared__ u16 Bs[2][256 * 32];

    // bijective XCD-chunked swizzle (m204) on linear bid, x-inner
    int nwg = gridDim.x * gridDim.y;
    int orig = blockIdx.y * gridDim.x + blockIdx.x;
    int qq = nwg >> 3, rr = nwg & 7;
    int xcd = orig & 7, cidx = orig >> 3;
    int wg = (xcd < rr ? xcd * (qq + 1) : rr * (qq + 1) + (xcd - rr) * qq) + cidx;
    int bx = wg % gridDim.x, by = wg / gridDim.x;
    int row0 = by * 256, col0 = bx * 256;

    int t = threadIdx.x, lane = t & 63, w = t >> 6;
    int wr = w >> 2, wc = w & 3;          // wave grid 2M x 4N; wave tile 128x64

    // staging geometry: each wave issues 2 glds per matrix; 64 lanes x 16B = 16 rows x 32 u16
    int cof = (lane & 3) * 8;            // u16 col offset
    int rin = lane >> 2;                 // 0..15 row within issue
    int ar0 = row0 + w * 32 + rin;       // 8 waves x 32 rows = 256
    int ar1 = ar0 + 16;
    auto mapfn = [&](int r) {
        if (r > M - 1) r = M - 1;
        if (map_cnlog2 >= 0) {
            int bt = r >> map_cnlog2;
            int of = r & ((1 << map_cnlog2) - 1);
            r = bt * NND + map_cstart + of;
        }
        return r;
    };
    const u16* aS0 = A + (long)mapfn(ar0) * K + cof;
    const u16* aS1 = A + (long)mapfn(ar1) * K + cof;
    const u16* bS0 = B + (long)(col0 + w * 32 + rin) * K + cof;
    const u16* bS1 = bS0 + 16L * K;
    int dof0 = (w * 32) * 32;
    int dof1 = (w * 32 + 16) * 32;

    f32x4 acc[8][4];
#pragma unroll
    for (int m = 0; m < 8; ++m)
#pragma unroll
        for (int n = 0; n < 4; ++n) acc[m][n] = f32x4{0.f, 0.f, 0.f, 0.f};

    int arl = wr * 128 + (lane & 15);
    int brl = wc * 64 + (lane & 15);
    int kk = (lane >> 4) * 8;

    auto stage = [&](int sel, int ko) {
        glds16(aS0 + ko, &As[sel][dof0]);
        glds16(aS1 + ko, &As[sel][dof1]);
        glds16(bS0 + ko, &Bs[sel][dof0]);
        glds16(bS1 + ko, &Bs[sel][dof1]);
    };
    auto compute = [&](int sel) {
        bf16x8 af[8], bfr[4];
#pragma unroll
        for (int m = 0; m < 8; ++m)
            af[m] = *(const bf16x8*)&As[sel][(arl + m * 16) * 32 + kk];
#pragma unroll
        for (int n = 0; n < 4; ++n)
            bfr[n] = *(const bf16x8*)&Bs[sel][(brl + n * 16) * 32 + kk];
#pragma unroll
        for (int m = 0; m < 8; ++m)
#pragma unroll
            for (int n = 0; n < 4; ++n)
                acc[m][n] = __builtin_amdgcn_mfma_f32_16x16x32_bf16(af[m], bfr[n], acc[m][n], 0, 0, 0);
    };

    int nk = K >> 5;                     // always even here (10 or 8)
    stage(0, 0);
    __syncthreads();                     // buf0 ready
    for (int kt = 0; kt < nk; kt += 2) {
        if (kt + 1 < nk) stage(1, (kt + 1) * 32);   // prefetch next into buf1
        compute(0);
        __syncthreads();                 // buf1 ready, buf0 free
        if (kt + 2 < nk) stage(0, (kt + 2) * 32);   // prefetch next+1 into buf0
        compute(1);
        __syncthreads();
    }

    int crow = row0 + wr * 128 + (lane >> 4) * 4;
    int ccol = col0 + wc * 64 + (lane & 15);
#pragma unroll
    for (int m = 0; m < 8; ++m) {
#pragma unroll
        for (int n = 0; n < 4; ++n) {
#pragma unroll
            for (int j = 0; j < 4; ++j) {
                int r = crow + m * 16 + j;
                int c = ccol + n * 16;
                if (r < M) {
                    if (STORE_BF16) ((u16*)C)[(long)r * N + c] = f2bf(acc[m][n][j]);
                    else            ((float*)C)[(long)r * N + c] = acc[m][n][j];
                }
            }
        }
    }
}

// ---------- leaves: h = tanh(sigmoid(i0)*tanh(u0)) ----------
__global__ __launch_bounds__(256) void k_leaf(const int* __restrict__ tok,
                                              const u16* __restrict__ vW,
                                              const float* __restrict__ qD,
                                              const float* __restrict__ b,
                                              u16* __restrict__ h) {
    int leaf = blockIdx.x, j = threadIdx.x;
    int bt = leaf >> 6, li = leaf & 63;        // 64 leaves per tree
    int row = bt * NND + 63 + li;
    long vwb = (long)tok[row] * 768;
    float ii = bf2f(vW[vwb + 256 + j]) + qD[9 * 768 + 256 + j] + b[256 + j];
    float uu = bf2f(vW[vwb + 512 + j]) + qD[9 * 768 + 512 + j] + b[512 + j];
    h[(long)row * HB + j] = f2bf(tanhf(sigm(ii) * tanhf(uu)));
}

// ---------- per-level node update reading merged g = h_child @ U.T (bf16) ----------
// g row layout per child c (compact level order): [0:256]=f-part, [256:512]=i, [512:768]=u
__global__ __launch_bounds__(256) void k_update(const int* __restrict__ tok,
                                                const int* __restrict__ dep,
                                                const u16* __restrict__ vW,
                                                const float* __restrict__ qD,
                                                const float* __restrict__ b,
                                                const u16* __restrict__ g,
                                                u16* __restrict__ h,
                                                float* __restrict__ out,
                                                int pstart, int pnl) {
    int pi = blockIdx.x, j = threadIdx.x;
    int bt = pi >> pnl, po = pi & ((1 << pnl) - 1);
    int pl = pstart + po;
    int gp  = bt * NND + pl;
    int gc1 = bt * NND + 2 * pl + 1, gc2 = gc1 + 1;
    long cc1 = (long)((bt << (pnl + 1)) + 2 * po) * 768;  // g rows of the two children
    long cc2 = cc1 + 768;
    long vwb = (long)tok[gp] * 768;
    int d1 = dep[gc1] * 768, d2 = dep[gc2] * 768;
    float xf = bf2f(vW[vwb + j]) + b[j];
    float f1 = sigm(xf + bf2f(g[cc1 + j]) + qD[d1 + j]);
    float f2 = sigm(xf + bf2f(g[cc2 + j]) + qD[d2 + j]);
    float ii = bf2f(vW[vwb + 256 + j]) + bf2f(g[cc1 + 256 + j]) + bf2f(g[cc2 + 256 + j])
             + qD[d1 + 256 + j] + qD[d2 + 256 + j] + b[256 + j];
    float uu = bf2f(vW[vwb + 512 + j]) + bf2f(g[cc1 + 512 + j]) + bf2f(g[cc2 + 512 + j])
             + qD[d1 + 512 + j] + qD[d2 + 512 + j] + b[512 + j];
    float h1 = bf2f(h[(long)gc1 * HB + j]);
    float h2 = bf2f(h[(long)gc2 * HB + j]);
    float hn = tanhf(sigm(ii) * tanhf(uu) + f1 * h1 + f2 * h2);
    if (out) out[(long)pi * HB + j] = hn;          // lv6: pi == bt, fp32 output
    else     h[(long)gp * HB + j] = f2bf(hn);
}

extern "C" void kernel_launch(void* const* d_in, const int* in_sizes, int n_in,
                              void* d_out, int out_size, void* d_ws, size_t ws_size,
                              hipStream_t stream) {
    const int*   tok = (const int*)d_in[0];
    const int*   dep = (const int*)d_in[1];
    const float* vec = (const float*)d_in[2];
    const float* q   = (const float*)d_in[3];
    const float* W   = (const float*)d_in[4];
    const float* U   = (const float*)d_in[5];
    const float* D   = (const float*)d_in[6];
    const float* b   = (const float*)d_in[7];

    char* ws = (char*)d_ws;
    size_t off = 0;
    auto alloc = [&](size_t bytes) {
        void* p = ws + off;
        off += (bytes + 255) & ~(size_t)255;
        return p;
    };
    float* qD = (float*)alloc((size_t)QQ * 768 * 4);
    u16*   vb = (u16*)alloc((size_t)VV * KEP * 2);
    u16*   Wb = (u16*)alloc((size_t)768 * KEP * 2);
    u16*   Ub = (u16*)alloc((size_t)768 * HB * 2);
    u16*   vW = (u16*)alloc((size_t)VV * 768 * 2);
    u16*   h  = (u16*)alloc((size_t)BT * NND * HB * 2);
    u16*   g  = (u16*)alloc((size_t)BT * 64 * 768 * 2);
    if (ws_size < off) return;  // ~177 MiB needed; zero output signals ws too small

    k_conv<<<(VV * (KEP / 8) + 255) / 256, 256, 0, stream>>>(vec, vb, VV, KE, KEP);
    k_conv<<<(768 * (KEP / 8) + 255) / 256, 256, 0, stream>>>(W, Wb, 768, KE, KEP);
    k_conv<<<(768 * (HB / 8) + 255) / 256, 256, 0, stream>>>(U, Ub, 768, HB, HB);
    k_qd<<<30, 256, 0, stream>>>(q, D, qD);

    // vW = (idx2vec @ W.T) as bf16, vocab-wide  (M=50000 -> 196 row-blocks, tail clamped)
    k_gemm<true><<<dim3(3, (VV + 255) / 256), 512, 0, stream>>>(
        vb, Wb, vW, VV, 768, KEP, -1, 0);

    k_leaf<<<BT * 64, 256, 0, stream>>>(tok, vW, qD, b, h);

    for (int lv = 1; lv <= 6; ++lv) {
        int pnl = 6 - lv;              // log2(parents per tree)
        int pn = 1 << pnl;
        int pstart = pn - 1;
        int cnl = pnl + 1;             // log2(children per tree)
        int cstart = (1 << cnl) - 1;
        int npT = BT * pn, ncT = BT * (1 << cnl);
        // g[children, 768] = h_child @ U.T  (A rows mapped into the tree layout)
        k_gemm<true><<<dim3(3, ncT / 256), 512, 0, stream>>>(
            h, Ub, g, ncT, 768, HB, cnl, cstart);
        k_update<<<npT, 256, 0, stream>>>(tok, dep, vW, qD, b, g, h,
                                          (lv == 6) ? (float*)d_out : nullptr,
                                          pstart, pnl);
    }
}

// Round 8
// 229.228 us; speedup vs baseline: 1.2109x; 1.2109x over previous
//
#include <hip/hip_runtime.h>

typedef unsigned short u16;
typedef u16 u16x4 __attribute__((ext_vector_type(4)));
typedef u16 u16x8 __attribute__((ext_vector_type(8)));
typedef __bf16 bf16x8 __attribute__((ext_vector_type(8)));
typedef float f32x4 __attribute__((ext_vector_type(4)));

#define HB   256    // H
#define NND  127    // nodes per tree
#define BT   512    // trees (batch)
#define KE   300    // E
#define KEP  320    // E padded to 32-multiple
#define VV   50000  // vocab
#define QQ   10     // Q

#define AS1 __attribute__((address_space(1)))
#define AS3 __attribute__((address_space(3)))

__device__ __forceinline__ u16 f2bf(float f) {
    unsigned int u = __builtin_bit_cast(unsigned int, f);
    u += 0x7FFFu + ((u >> 16) & 1u);          // RNE
    return (u16)(u >> 16);
}
__device__ __forceinline__ float bf2f(u16 h) {
    unsigned int u = ((unsigned int)h) << 16;
    return __builtin_bit_cast(float, u);
}
__device__ __forceinline__ float sigm(float x) { return 1.f / (1.f + __expf(-x)); }

__device__ __forceinline__ void glds16(const u16* g, u16* l) {
    __builtin_amdgcn_global_load_lds((const AS1 void*)g, (AS3 void*)l, 16, 0, 0);
}

// ---------- vocab embedding fp32 -> bf16 convert, K=300 -> 320 zero-pad ----------
__global__ __launch_bounds__(256) void k_conv(const float* __restrict__ src,
                                              u16* __restrict__ dst,
                                              int rows, int K, int Kp) {
    int i = blockIdx.x * 256 + threadIdx.x;   // one 8-elem chunk per thread
    int nch = Kp >> 3;
    if (i >= rows * nch) return;
    int r = i / nch, c = (i - r * nch) * 8;
    const float* s = src + (long)r * K + c;
    u16x8 o;
#pragma unroll
    for (int e = 0; e < 8; ++e) o[e] = (c + e < K) ? f2bf(s[e]) : (u16)0;
    *(u16x8*)(dst + (long)i * 8) = o;
}

// ---------- merged prep: convert W (120 blks), U (96 blks), qD = q@D.T (30 blks) ----------
__global__ __launch_bounds__(256) void k_prep(const float* __restrict__ W,
                                              const float* __restrict__ U,
                                              const float* __restrict__ q,
                                              const float* __restrict__ D,
                                              u16* __restrict__ Wb,
                                              u16* __restrict__ Ub,
                                              float* __restrict__ qD) {
    int blk = blockIdx.x;
    if (blk < 120) {                       // W: 768 rows, K=300 -> Kp=320 (40 chunks)
        int i = blk * 256 + threadIdx.x;
        if (i < 768 * 40) {
            int r = i / 40, c = (i - r * 40) * 8;
            const float* s = W + (long)r * KE + c;
            u16x8 o;
#pragma unroll
            for (int e = 0; e < 8; ++e) o[e] = (c + e < KE) ? f2bf(s[e]) : (u16)0;
            *(u16x8*)(Wb + (long)i * 8) = o;
        }
    } else if (blk < 216) {                // U: 768 rows, K=Kp=256 (32 chunks)
        int i = (blk - 120) * 256 + threadIdx.x;
        if (i < 768 * 32) {
            int r = i / 32, c = (i - r * 32) * 8;
            const float* s = U + (long)r * HB + c;
            u16x8 o;
#pragma unroll
            for (int e = 0; e < 8; ++e) o[e] = f2bf(s[e]);
            *(u16x8*)(Ub + (long)i * 8) = o;
        }
    } else {                               // qD[i] over QQ*768
        int i = (blk - 216) * 256 + threadIdx.x;
        if (i < QQ * 768) {
            int qi = i / 768, col = i - qi * 768;
            const float* qr = q + qi * HB;
            const float* dr = D + col * HB;
            float s = 0.f;
            for (int k = 0; k < HB; ++k) s += qr[k] * dr[k];
            qD[i] = s;
        }
    }
}

// ---------- bf16 NT GEMM: global_load_lds(16B), 128x128 tile ----------
// Depth-3 pipeline, 4 LDS buffers, counted vmcnt (T4) — best measured variant (R6), frozen.
// C[M,N] = A[M,K] * B[N,K]^T ; A,B bf16 row-major, K/32 = nk >= 4, N % 128 == 0.
// optional A-row map: global_row = (r>>cnlog2)*127 + cstart + (r & ((1<<cnlog2)-1))
template <bool STORE_BF16>
__global__ __launch_bounds__(256) void k_gemm(const u16* __restrict__ A,
                                              const u16* __restrict__ B,
                                              void* __restrict__ C,
                                              int M, int N, int K,
                                              int map_cnlog2, int map_cstart) {
    __shared__ u16 As[4][128 * 32];
    __shared__ u16 Bs[4][128 * 32];

    // bijective XCD-chunked swizzle (m204) on linear bid, x-inner
    int nwg = gridDim.x * gridDim.y;
    int orig = blockIdx.y * gridDim.x + blockIdx.x;
    int qq = nwg >> 3, rr = nwg & 7;
    int xcd = orig & 7, cidx = orig >> 3;
    int wg = (xcd < rr ? xcd * (qq + 1) : rr * (qq + 1) + (xcd - rr) * qq) + cidx;
    int bx = wg % gridDim.x, by = wg / gridDim.x;
    int row0 = by * 128, col0 = bx * 128;

    int t = threadIdx.x, lane = t & 63, w = t >> 6;
    int wr = w >> 1, wc = w & 1;

    // staging geometry: per wave-issue, 64 lanes x 16B = 16 rows x 32 u16
    int cof = (lane & 3) * 8;            // u16 col offset
    int rin = lane >> 2;                 // 0..15 row within issue
    int ar0 = row0 + w * 32 + rin;
    int ar1 = ar0 + 16;
    auto mapfn = [&](int r) {
        if (r > M - 1) r = M - 1;
        if (map_cnlog2 >= 0) {
            int bt = r >> map_cnlog2;
            int of = r & ((1 << map_cnlog2) - 1);
            r = bt * NND + map_cstart + of;
        }
        return r;
    };
    const u16* aS0 = A + (long)mapfn(ar0) * K + cof;
    const u16* aS1 = A + (long)mapfn(ar1) * K + cof;
    const u16* bS0 = B + (long)(col0 + w * 32 + rin) * K + cof;
    const u16* bS1 = bS0 + 16L * K;
    int dof0 = (w * 32) * 32;
    int dof1 = (w * 32 + 16) * 32;

    f32x4 acc[4][4];
#pragma unroll
    for (int m = 0; m < 4; ++m)
#pragma unroll
        for (int n = 0; n < 4; ++n) acc[m][n] = f32x4{0.f, 0.f, 0.f, 0.f};

    int arl = wr * 64 + (lane & 15);
    int brl = wc * 64 + (lane & 15);
    int kk = (lane >> 4) * 8;

    auto stage = [&](int sel, int ko) {
        glds16(aS0 + ko, &As[sel][dof0]);
        glds16(aS1 + ko, &As[sel][dof1]);
        glds16(bS0 + ko, &Bs[sel][dof0]);
        glds16(bS1 + ko, &Bs[sel][dof1]);
    };
    auto compute = [&](int sel) {
        bf16x8 af[4], bfr[4];
#pragma unroll
        for (int m = 0; m < 4; ++m)
            af[m] = *(const bf16x8*)&As[sel][(arl + m * 16) * 32 + kk];
#pragma unroll
        for (int n = 0; n < 4; ++n)
            bfr[n] = *(const bf16x8*)&Bs[sel][(brl + n * 16) * 32 + kk];
#pragma unroll
        for (int m = 0; m < 4; ++m)
#pragma unroll
            for (int n = 0; n < 4; ++n)
                acc[m][n] = __builtin_amdgcn_mfma_f32_16x16x32_bf16(af[m], bfr[n], acc[m][n], 0, 0, 0);
    };

    int nk = K >> 5;                     // 8 or 10 here (>= 4 required)
    stage(0, 0); stage(1, 32); stage(2, 64);     // 12 loads/wave in flight
    for (int kt = 0; kt < nk - 3; ++kt) {
        asm volatile("s_waitcnt vmcnt(8)" ::: "memory");
        __builtin_amdgcn_s_barrier();
        __builtin_amdgcn_sched_barrier(0);
        compute(kt & 3);
        stage((kt + 3) & 3, (kt + 3) * 32);
    }
    asm volatile("s_waitcnt vmcnt(8)" ::: "memory");
    __builtin_amdgcn_s_barrier();
    __builtin_amdgcn_sched_barrier(0);
    compute((nk - 3) & 3);
    asm volatile("s_waitcnt vmcnt(4)" ::: "memory");
    __builtin_amdgcn_s_barrier();
    __builtin_amdgcn_sched_barrier(0);
    compute((nk - 2) & 3);
    asm volatile("s_waitcnt vmcnt(0)" ::: "memory");
    __builtin_amdgcn_s_barrier();
    __builtin_amdgcn_sched_barrier(0);
    compute((nk - 1) & 3);

    int crow = row0 + wr * 64 + (lane >> 4) * 4;
    int ccol = col0 + wc * 64 + (lane & 15);
#pragma unroll
    for (int m = 0; m < 4; ++m) {
#pragma unroll
        for (int n = 0; n < 4; ++n) {
#pragma unroll
            for (int j = 0; j < 4; ++j) {
                int r = crow + m * 16 + j;
                int c = ccol + n * 16;
                if (r < M) {
                    if (STORE_BF16) ((u16*)C)[(long)r * N + c] = f2bf(acc[m][n][j]);
                    else            ((float*)C)[(long)r * N + c] = acc[m][n][j];
                }
            }
        }
    }
}

// ---------- leaves, vectorized: one wave per leaf, 4 j per lane ----------
__global__ __launch_bounds__(256) void k_leaf(const int* __restrict__ tok,
                                              const u16* __restrict__ vW,
                                              const float* __restrict__ qD,
                                              const float* __restrict__ b,
                                              u16* __restrict__ h) {
    int w = threadIdx.x >> 6, t = threadIdx.x & 63;
    int leaf = blockIdx.x * 4 + w;             // 0..32767
    int j = t * 4;
    int bt = leaf >> 6, li = leaf & 63;        // 64 leaves per tree
    int row = bt * NND + 63 + li;
    long vwb = (long)tok[row] * 768;
    u16x4 vi = *(const u16x4*)(vW + vwb + 256 + j);
    u16x4 vu = *(const u16x4*)(vW + vwb + 512 + j);
    f32x4 qi = *(const f32x4*)(qD + 9 * 768 + 256 + j);
    f32x4 qu = *(const f32x4*)(qD + 9 * 768 + 512 + j);
    f32x4 bi = *(const f32x4*)(b + 256 + j);
    f32x4 bu = *(const f32x4*)(b + 512 + j);
    u16x4 o;
#pragma unroll
    for (int e = 0; e < 4; ++e) {
        float ii = bf2f(vi[e]) + qi[e] + bi[e];
        float uu = bf2f(vu[e]) + qu[e] + bu[e];
        o[e] = f2bf(tanhf(sigm(ii) * tanhf(uu)));
    }
    *(u16x4*)(h + (long)row * HB + j) = o;
}

// ---------- per-level update, vectorized: one wave per parent, 4 j per lane ----------
// g row layout per child c (compact level order): [0:256]=f-part, [256:512]=i, [512:768]=u
__global__ __launch_bounds__(256) void k_update(const int* __restrict__ tok,
                                                const int* __restrict__ dep,
                                                const u16* __restrict__ vW,
                                                const float* __restrict__ qD,
                                                const float* __restrict__ b,
                                                const u16* __restrict__ g,
                                                u16* __restrict__ h,
                                                float* __restrict__ out,
                                                int pstart, int pnl) {
    int w = threadIdx.x >> 6, t = threadIdx.x & 63;
    int pi = blockIdx.x * 4 + w;
    int j = t * 4;
    int bt = pi >> pnl, po = pi & ((1 << pnl) - 1);
    int pl = pstart + po;
    int gp  = bt * NND + pl;
    int gc1 = bt * NND + 2 * pl + 1, gc2 = gc1 + 1;
    long cc1 = (long)((bt << (pnl + 1)) + 2 * po) * 768;  // g rows of the two children
    long cc2 = cc1 + 768;
    long vwb = (long)tok[gp] * 768;
    int d1 = dep[gc1] * 768, d2 = dep[gc2] * 768;
    u16x4 vf  = *(const u16x4*)(vW + vwb + j);
    u16x4 vi  = *(const u16x4*)(vW + vwb + 256 + j);
    u16x4 vu  = *(const u16x4*)(vW + vwb + 512 + j);
    u16x4 gf1 = *(const u16x4*)(g + cc1 + j);
    u16x4 gf2 = *(const u16x4*)(g + cc2 + j);
    u16x4 gi1 = *(const u16x4*)(g + cc1 + 256 + j);
    u16x4 gi2 = *(const u16x4*)(g + cc2 + 256 + j);
    u16x4 gu1 = *(const u16x4*)(g + cc1 + 512 + j);
    u16x4 gu2 = *(const u16x4*)(g + cc2 + 512 + j);
    f32x4 qf1 = *(const f32x4*)(qD + d1 + j);
    f32x4 qf2 = *(const f32x4*)(qD + d2 + j);
    f32x4 qi1 = *(const f32x4*)(qD + d1 + 256 + j);
    f32x4 qi2 = *(const f32x4*)(qD + d2 + 256 + j);
    f32x4 qu1 = *(const f32x4*)(qD + d1 + 512 + j);
    f32x4 qu2 = *(const f32x4*)(qD + d2 + 512 + j);
    f32x4 bf_ = *(const f32x4*)(b + j);
    f32x4 bi_ = *(const f32x4*)(b + 256 + j);
    f32x4 bu_ = *(const f32x4*)(b + 512 + j);
    u16x4 h1v = *(const u16x4*)(h + (long)gc1 * HB + j);
    u16x4 h2v = *(const u16x4*)(h + (long)gc2 * HB + j);
    f32x4 res;
    u16x4 resb;
#pragma unroll
    for (int e = 0; e < 4; ++e) {
        float xf = bf2f(vf[e]) + bf_[e];
        float f1 = sigm(xf + bf2f(gf1[e]) + qf1[e]);
        float f2 = sigm(xf + bf2f(gf2[e]) + qf2[e]);
        float ii = bf2f(vi[e]) + bf2f(gi1[e]) + bf2f(gi2[e]) + qi1[e] + qi2[e] + bi_[e];
        float uu = bf2f(vu[e]) + bf2f(gu1[e]) + bf2f(gu2[e]) + qu1[e] + qu2[e] + bu_[e];
        float hn = tanhf(sigm(ii) * tanhf(uu) + f1 * bf2f(h1v[e]) + f2 * bf2f(h2v[e]));
        res[e] = hn;
        resb[e] = f2bf(hn);
    }
    if (out) *(f32x4*)(out + (long)pi * HB + j) = res;     // lv6: pi == bt, fp32 output
    else     *(u16x4*)(h + (long)gp * HB + j) = resb;
}

extern "C" void kernel_launch(void* const* d_in, const int* in_sizes, int n_in,
                              void* d_out, int out_size, void* d_ws, size_t ws_size,
                              hipStream_t stream) {
    const int*   tok = (const int*)d_in[0];
    const int*   dep = (const int*)d_in[1];
    const float* vec = (const float*)d_in[2];
    const float* q   = (const float*)d_in[3];
    const float* W   = (const float*)d_in[4];
    const float* U   = (const float*)d_in[5];
    const float* D   = (const float*)d_in[6];
    const float* b   = (const float*)d_in[7];

    char* ws = (char*)d_ws;
    size_t off = 0;
    auto alloc = [&](size_t bytes) {
        void* p = ws + off;
        off += (bytes + 255) & ~(size_t)255;
        return p;
    };
    float* qD = (float*)alloc((size_t)QQ * 768 * 4);
    u16*   vb = (u16*)alloc((size_t)VV * KEP * 2);
    u16*   Wb = (u16*)alloc((size_t)768 * KEP * 2);
    u16*   Ub = (u16*)alloc((size_t)768 * HB * 2);
    u16*   vW = (u16*)alloc((size_t)VV * 768 * 2);
    u16*   h  = (u16*)alloc((size_t)BT * NND * HB * 2);
    u16*   g  = (u16*)alloc((size_t)BT * 64 * 768 * 2);
    if (ws_size < off) return;  // ~177 MiB needed; zero output signals ws too small

    k_conv<<<(VV * (KEP / 8) + 255) / 256, 256, 0, stream>>>(vec, vb, VV, KE, KEP);
    k_prep<<<246, 256, 0, stream>>>(W, U, q, D, Wb, Ub, qD);

    // vW = (idx2vec @ W.T) as bf16, vocab-wide
    k_gemm<true><<<dim3(6, (VV + 127) / 128), 256, 0, stream>>>(
        vb, Wb, vW, VV, 768, KEP, -1, 0);

    k_leaf<<<BT * 64 / 4, 256, 0, stream>>>(tok, vW, qD, b, h);

    for (int lv = 1; lv <= 6; ++lv) {
        int pnl = 6 - lv;              // log2(parents per tree)
        int pn = 1 << pnl;
        int pstart = pn - 1;
        int cnl = pnl + 1;             // log2(children per tree)
        int cstart = (1 << cnl) - 1;
        int npT = BT * pn, ncT = BT * (1 << cnl);
        // g[children, 768] = h_child @ U.T  (A rows mapped into the tree layout)
        k_gemm<true><<<dim3(6, ncT / 128), 256, 0, stream>>>(
            h, Ub, g, ncT, 768, HB, cnl, cstart);
        k_update<<<npT / 4, 256, 0, stream>>>(tok, dep, vW, qD, b, g, h,
                                              (lv == 6) ? (float*)d_out : nullptr,
                                              pstart, pnl);
    }
}

// Round 9
// 221.518 us; speedup vs baseline: 1.2531x; 1.0348x over previous
//
#include <hip/hip_runtime.h>

typedef unsigned short u16;
typedef u16 u16x4 __attribute__((ext_vector_type(4)));
typedef u16 u16x8 __attribute__((ext_vector_type(8)));
typedef __bf16 bf16x8 __attribute__((ext_vector_type(8)));
typedef float f32x4 __attribute__((ext_vector_type(4)));

#define HB   256    // H
#define NND  127    // nodes per tree
#define BT   512    // trees (batch)
#define KE   300    // E
#define KEP  320    // E padded to 32-multiple
#define VV   50000  // vocab
#define QQ   10     // Q

#define AS1 __attribute__((address_space(1)))
#define AS3 __attribute__((address_space(3)))

__device__ __forceinline__ u16 f2bf(float f) {
    unsigned int u = __builtin_bit_cast(unsigned int, f);
    u += 0x7FFFu + ((u >> 16) & 1u);          // RNE
    return (u16)(u >> 16);
}
__device__ __forceinline__ float bf2f(u16 h) {
    unsigned int u = ((unsigned int)h) << 16;
    return __builtin_bit_cast(float, u);
}
__device__ __forceinline__ float sigm(float x) { return 1.f / (1.f + __expf(-x)); }

__device__ __forceinline__ void glds16(const u16* g, u16* l) {
    __builtin_amdgcn_global_load_lds((const AS1 void*)g, (AS3 void*)l, 16, 0, 0);
}

// ---------- merged prep: convert W (120 blks), U (96 blks), qD = q@D.T (30 blks) ----------
__global__ __launch_bounds__(256) void k_prep(const float* __restrict__ W,
                                              const float* __restrict__ U,
                                              const float* __restrict__ q,
                                              const float* __restrict__ D,
                                              u16* __restrict__ Wb,
                                              u16* __restrict__ Ub,
                                              float* __restrict__ qD) {
    int blk = blockIdx.x;
    if (blk < 120) {                       // W: 768 rows, K=300 -> Kp=320 (40 chunks)
        int i = blk * 256 + threadIdx.x;
        if (i < 768 * 40) {
            int r = i / 40, c = (i - r * 40) * 8;
            const float* s = W + (long)r * KE + c;
            u16x8 o;
#pragma unroll
            for (int e = 0; e < 8; ++e) o[e] = (c + e < KE) ? f2bf(s[e]) : (u16)0;
            *(u16x8*)(Wb + (long)i * 8) = o;
        }
    } else if (blk < 216) {                // U: 768 rows, K=Kp=256 (32 chunks)
        int i = (blk - 120) * 256 + threadIdx.x;
        if (i < 768 * 32) {
            int r = i / 32, c = (i - r * 32) * 8;
            const float* s = U + (long)r * HB + c;
            u16x8 o;
#pragma unroll
            for (int e = 0; e < 8; ++e) o[e] = f2bf(s[e]);
            *(u16x8*)(Ub + (long)i * 8) = o;
        }
    } else {                               // qD[i] over QQ*768
        int i = (blk - 216) * 256 + threadIdx.x;
        if (i < QQ * 768) {
            int qi = i / 768, col = i - qi * 768;
            const float* qr = q + qi * HB;
            const float* dr = D + col * HB;
            float s = 0.f;
            for (int k = 0; k < HB; ++k) s += qr[k] * dr[k];
            qD[i] = s;
        }
    }
}

// ---------- vW GEMM with fused A-conversion ----------
// C[VV,768] = vec[VV,300(fp32)] @ Wb[768,320(bf16)]^T
// A: reg-staged fp32 -> cvt bf16 -> ds_write (T14: issue-early, write-late).
// B: global_load_lds. One barrier per K-step, 2-phase double buffer.
__global__ __launch_bounds__(256) void k_gemmA(const float* __restrict__ A,
                                               const u16* __restrict__ B,
                                               u16* __restrict__ C) {
    __shared__ u16 As[2][128 * 32];
    __shared__ u16 Bs[2][128 * 32];
    const int M = VV, N = 768;

    // bijective XCD-chunked swizzle (m204)
    int nwg = gridDim.x * gridDim.y;
    int orig = blockIdx.y * gridDim.x + blockIdx.x;
    int qq = nwg >> 3, rr = nwg & 7;
    int xcd = orig & 7, cidx = orig >> 3;
    int wg = (xcd < rr ? xcd * (qq + 1) : rr * (qq + 1) + (xcd - rr) * qq) + cidx;
    int bx = wg % gridDim.x, by = wg / gridDim.x;
    int row0 = by * 128, col0 = bx * 128;

    int t = threadIdx.x, lane = t & 63, w = t >> 6;
    int wr = w >> 1, wc = w & 1;

    // A staging (regs): thread covers tile row sr, 16-col half shf
    int sr = t >> 1, shf = (t & 1) * 16;
    int ga = row0 + sr; if (ga > M - 1) ga = M - 1;
    const float* arow = A + (long)ga * KE;

    // B staging (glds): per wave-issue, 64 lanes x 16B = 16 rows x 32 u16
    int cof = (lane & 3) * 8;
    int rin = lane >> 2;
    const u16* bS0 = B + (long)(col0 + w * 32 + rin) * KEP + cof;
    const u16* bS1 = bS0 + 16L * KEP;
    int dof0 = (w * 32) * 32;
    int dof1 = (w * 32 + 16) * 32;

    f32x4 acc[4][4];
#pragma unroll
    for (int m = 0; m < 4; ++m)
#pragma unroll
        for (int n = 0; n < 4; ++n) acc[m][n] = f32x4{0.f, 0.f, 0.f, 0.f};

    int arl = wr * 64 + (lane & 15);
    int brl = wc * 64 + (lane & 15);
    int kk = (lane >> 4) * 8;

    float ar[16];
    auto issueA = [&](int kt) {
        int kb = kt * 32 + shf;
        if (kb + 16 <= KE) {
#pragma unroll
            for (int v = 0; v < 4; ++v) {
                f32x4 x = *(const f32x4*)(arow + kb + v * 4);
#pragma unroll
                for (int e = 0; e < 4; ++e) ar[v * 4 + e] = x[e];
            }
        } else {
#pragma unroll
            for (int e = 0; e < 16; ++e) ar[e] = (kb + e < KE) ? arow[kb + e] : 0.f;
        }
    };
    auto writeA = [&](int sel) {
        u16x8 o0, o1;
#pragma unroll
        for (int e = 0; e < 8; ++e) {
            o0[e] = f2bf(ar[e]);
            o1[e] = f2bf(ar[8 + e]);
        }
        *(u16x8*)&As[sel][sr * 32 + shf] = o0;
        *(u16x8*)&As[sel][sr * 32 + shf + 8] = o1;
    };
    auto stageB = [&](int sel, int ko) {
        glds16(bS0 + ko, &Bs[sel][dof0]);
        glds16(bS1 + ko, &Bs[sel][dof1]);
    };
    auto compute = [&](int sel) {
        bf16x8 af[4], bfr[4];
#pragma unroll
        for (int m = 0; m < 4; ++m)
            af[m] = *(const bf16x8*)&As[sel][(arl + m * 16) * 32 + kk];
#pragma unroll
        for (int n = 0; n < 4; ++n)
            bfr[n] = *(const bf16x8*)&Bs[sel][(brl + n * 16) * 32 + kk];
#pragma unroll
        for (int m = 0; m < 4; ++m)
#pragma unroll
            for (int n = 0; n < 4; ++n)
                acc[m][n] = __builtin_amdgcn_mfma_f32_16x16x32_bf16(af[m], bfr[n], acc[m][n], 0, 0, 0);
    };

    const int nk = KEP / 32;             // 10
    issueA(0); stageB(0, 0);
    writeA(0);                           // waits A-loads (once)
    __syncthreads();                     // drains B glds, publishes A writes
    for (int kt = 0; kt < nk; ++kt) {
        int cur = kt & 1;
        if (kt + 1 < nk) { issueA(kt + 1); stageB(cur ^ 1, (kt + 1) * 32); }
        compute(cur);
        if (kt + 1 < nk) writeA(cur ^ 1);  // A-loads flew during compute
        __syncthreads();                   // publish A+B of kt+1; all done reading cur
    }

    int crow = row0 + wr * 64 + (lane >> 4) * 4;
    int ccol = col0 + wc * 64 + (lane & 15);
#pragma unroll
    for (int m = 0; m < 4; ++m) {
#pragma unroll
        for (int n = 0; n < 4; ++n) {
#pragma unroll
            for (int j = 0; j < 4; ++j) {
                int r = crow + m * 16 + j;
                if (r < M) ((u16*)C)[(long)r * N + ccol + n * 16] = f2bf(acc[m][n][j]);
            }
        }
    }
}

// ---------- bf16 NT GEMM: global_load_lds(16B), 128x128 tile ----------
// Depth-3 pipeline, 4 LDS buffers, counted vmcnt (T4) — best measured variant (R6), frozen.
// C[M,N] = A[M,K] * B[N,K]^T ; A,B bf16 row-major, K/32 = nk >= 4, N % 128 == 0.
// optional A-row map: global_row = (r>>cnlog2)*127 + cstart + (r & ((1<<cnlog2)-1))
template <bool STORE_BF16>
__global__ __launch_bounds__(256) void k_gemm(const u16* __restrict__ A,
                                              const u16* __restrict__ B,
                                              void* __restrict__ C,
                                              int M, int N, int K,
                                              int map_cnlog2, int map_cstart) {
    __shared__ u16 As[4][128 * 32];
    __shared__ u16 Bs[4][128 * 32];

    // bijective XCD-chunked swizzle (m204) on linear bid, x-inner
    int nwg = gridDim.x * gridDim.y;
    int orig = blockIdx.y * gridDim.x + blockIdx.x;
    int qq = nwg >> 3, rr = nwg & 7;
    int xcd = orig & 7, cidx = orig >> 3;
    int wg = (xcd < rr ? xcd * (qq + 1) : rr * (qq + 1) + (xcd - rr) * qq) + cidx;
    int bx = wg % gridDim.x, by = wg / gridDim.x;
    int row0 = by * 128, col0 = bx * 128;

    int t = threadIdx.x, lane = t & 63, w = t >> 6;
    int wr = w >> 1, wc = w & 1;

    // staging geometry: per wave-issue, 64 lanes x 16B = 16 rows x 32 u16
    int cof = (lane & 3) * 8;            // u16 col offset
    int rin = lane >> 2;                 // 0..15 row within issue
    int ar0 = row0 + w * 32 + rin;
    int ar1 = ar0 + 16;
    auto mapfn = [&](int r) {
        if (r > M - 1) r = M - 1;
        if (map_cnlog2 >= 0) {
            int bt = r >> map_cnlog2;
            int of = r & ((1 << map_cnlog2) - 1);
            r = bt * NND + map_cstart + of;
        }
        return r;
    };
    const u16* aS0 = A + (long)mapfn(ar0) * K + cof;
    const u16* aS1 = A + (long)mapfn(ar1) * K + cof;
    const u16* bS0 = B + (long)(col0 + w * 32 + rin) * K + cof;
    const u16* bS1 = bS0 + 16L * K;
    int dof0 = (w * 32) * 32;
    int dof1 = (w * 32 + 16) * 32;

    f32x4 acc[4][4];
#pragma unroll
    for (int m = 0; m < 4; ++m)
#pragma unroll
        for (int n = 0; n < 4; ++n) acc[m][n] = f32x4{0.f, 0.f, 0.f, 0.f};

    int arl = wr * 64 + (lane & 15);
    int brl = wc * 64 + (lane & 15);
    int kk = (lane >> 4) * 8;

    auto stage = [&](int sel, int ko) {
        glds16(aS0 + ko, &As[sel][dof0]);
        glds16(aS1 + ko, &As[sel][dof1]);
        glds16(bS0 + ko, &Bs[sel][dof0]);
        glds16(bS1 + ko, &Bs[sel][dof1]);
    };
    auto compute = [&](int sel) {
        bf16x8 af[4], bfr[4];
#pragma unroll
        for (int m = 0; m < 4; ++m)
            af[m] = *(const bf16x8*)&As[sel][(arl + m * 16) * 32 + kk];
#pragma unroll
        for (int n = 0; n < 4; ++n)
            bfr[n] = *(const bf16x8*)&Bs[sel][(brl + n * 16) * 32 + kk];
#pragma unroll
        for (int m = 0; m < 4; ++m)
#pragma unroll
            for (int n = 0; n < 4; ++n)
                acc[m][n] = __builtin_amdgcn_mfma_f32_16x16x32_bf16(af[m], bfr[n], acc[m][n], 0, 0, 0);
    };

    int nk = K >> 5;                     // 8 here (>= 4 required)
    stage(0, 0); stage(1, 32); stage(2, 64);     // 12 loads/wave in flight
    for (int kt = 0; kt < nk - 3; ++kt) {
        asm volatile("s_waitcnt vmcnt(8)" ::: "memory");
        __builtin_amdgcn_s_barrier();
        __builtin_amdgcn_sched_barrier(0);
        compute(kt & 3);
        stage((kt + 3) & 3, (kt + 3) * 32);
    }
    asm volatile("s_waitcnt vmcnt(8)" ::: "memory");
    __builtin_amdgcn_s_barrier();
    __builtin_amdgcn_sched_barrier(0);
    compute((nk - 3) & 3);
    asm volatile("s_waitcnt vmcnt(4)" ::: "memory");
    __builtin_amdgcn_s_barrier();
    __builtin_amdgcn_sched_barrier(0);
    compute((nk - 2) & 3);
    asm volatile("s_waitcnt vmcnt(0)" ::: "memory");
    __builtin_amdgcn_s_barrier();
    __builtin_amdgcn_sched_barrier(0);
    compute((nk - 1) & 3);

    int crow = row0 + wr * 64 + (lane >> 4) * 4;
    int ccol = col0 + wc * 64 + (lane & 15);
#pragma unroll
    for (int m = 0; m < 4; ++m) {
#pragma unroll
        for (int n = 0; n < 4; ++n) {
#pragma unroll
            for (int j = 0; j < 4; ++j) {
                int r = crow + m * 16 + j;
                int c = ccol + n * 16;
                if (r < M) {
                    if (STORE_BF16) ((u16*)C)[(long)r * N + c] = f2bf(acc[m][n][j]);
                    else            ((float*)C)[(long)r * N + c] = acc[m][n][j];
                }
            }
        }
    }
}

// ---------- leaves, vectorized: one wave per leaf, 4 j per lane ----------
__global__ __launch_bounds__(256) void k_leaf(const int* __restrict__ tok,
                                              const u16* __restrict__ vW,
                                              const float* __restrict__ qD,
                                              const float* __restrict__ b,
                                              u16* __restrict__ h) {
    int w = threadIdx.x >> 6, t = threadIdx.x & 63;
    int leaf = blockIdx.x * 4 + w;             // 0..32767
    int j = t * 4;
    int bt = leaf >> 6, li = leaf & 63;        // 64 leaves per tree
    int row = bt * NND + 63 + li;
    long vwb = (long)tok[row] * 768;
    u16x4 vi = *(const u16x4*)(vW + vwb + 256 + j);
    u16x4 vu = *(const u16x4*)(vW + vwb + 512 + j);
    f32x4 qi = *(const f32x4*)(qD + 9 * 768 + 256 + j);
    f32x4 qu = *(const f32x4*)(qD + 9 * 768 + 512 + j);
    f32x4 bi = *(const f32x4*)(b + 256 + j);
    f32x4 bu = *(const f32x4*)(b + 512 + j);
    u16x4 o;
#pragma unroll
    for (int e = 0; e < 4; ++e) {
        float ii = bf2f(vi[e]) + qi[e] + bi[e];
        float uu = bf2f(vu[e]) + qu[e] + bu[e];
        o[e] = f2bf(tanhf(sigm(ii) * tanhf(uu)));
    }
    *(u16x4*)(h + (long)row * HB + j) = o;
}

// ---------- per-level update, vectorized: one wave per parent, 4 j per lane ----------
// g row layout per child c (compact level order): [0:256]=f-part, [256:512]=i, [512:768]=u
__global__ __launch_bounds__(256) void k_update(const int* __restrict__ tok,
                                                const int* __restrict__ dep,
                                                const u16* __restrict__ vW,
                                                const float* __restrict__ qD,
                                                const float* __restrict__ b,
                                                const u16* __restrict__ g,
                                                u16* __restrict__ h,
                                                float* __restrict__ out,
                                                int pstart, int pnl) {
    int w = threadIdx.x >> 6, t = threadIdx.x & 63;
    int pi = blockIdx.x * 4 + w;
    int j = t * 4;
    int bt = pi >> pnl, po = pi & ((1 << pnl) - 1);
    int pl = pstart + po;
    int gp  = bt * NND + pl;
    int gc1 = bt * NND + 2 * pl + 1, gc2 = gc1 + 1;
    long cc1 = (long)((bt << (pnl + 1)) + 2 * po) * 768;  // g rows of the two children
    long cc2 = cc1 + 768;
    long vwb = (long)tok[gp] * 768;
    int d1 = dep[gc1] * 768, d2 = dep[gc2] * 768;
    u16x4 vf  = *(const u16x4*)(vW + vwb + j);
    u16x4 vi  = *(const u16x4*)(vW + vwb + 256 + j);
    u16x4 vu  = *(const u16x4*)(vW + vwb + 512 + j);
    u16x4 gf1 = *(const u16x4*)(g + cc1 + j);
    u16x4 gf2 = *(const u16x4*)(g + cc2 + j);
    u16x4 gi1 = *(const u16x4*)(g + cc1 + 256 + j);
    u16x4 gi2 = *(const u16x4*)(g + cc2 + 256 + j);
    u16x4 gu1 = *(const u16x4*)(g + cc1 + 512 + j);
    u16x4 gu2 = *(const u16x4*)(g + cc2 + 512 + j);
    f32x4 qf1 = *(const f32x4*)(qD + d1 + j);
    f32x4 qf2 = *(const f32x4*)(qD + d2 + j);
    f32x4 qi1 = *(const f32x4*)(qD + d1 + 256 + j);
    f32x4 qi2 = *(const f32x4*)(qD + d2 + 256 + j);
    f32x4 qu1 = *(const f32x4*)(qD + d1 + 512 + j);
    f32x4 qu2 = *(const f32x4*)(qD + d2 + 512 + j);
    f32x4 bf_ = *(const f32x4*)(b + j);
    f32x4 bi_ = *(const f32x4*)(b + 256 + j);
    f32x4 bu_ = *(const f32x4*)(b + 512 + j);
    u16x4 h1v = *(const u16x4*)(h + (long)gc1 * HB + j);
    u16x4 h2v = *(const u16x4*)(h + (long)gc2 * HB + j);
    f32x4 res;
    u16x4 resb;
#pragma unroll
    for (int e = 0; e < 4; ++e) {
        float xf = bf2f(vf[e]) + bf_[e];
        float f1 = sigm(xf + bf2f(gf1[e]) + qf1[e]);
        float f2 = sigm(xf + bf2f(gf2[e]) + qf2[e]);
        float ii = bf2f(vi[e]) + bf2f(gi1[e]) + bf2f(gi2[e]) + qi1[e] + qi2[e] + bi_[e];
        float uu = bf2f(vu[e]) + bf2f(gu1[e]) + bf2f(gu2[e]) + qu1[e] + qu2[e] + bu_[e];
        float hn = tanhf(sigm(ii) * tanhf(uu) + f1 * bf2f(h1v[e]) + f2 * bf2f(h2v[e]));
        res[e] = hn;
        resb[e] = f2bf(hn);
    }
    if (out) *(f32x4*)(out + (long)pi * HB + j) = res;     // lv6: pi == bt, fp32 output
    else     *(u16x4*)(h + (long)gp * HB + j) = resb;
}

extern "C" void kernel_launch(void* const* d_in, const int* in_sizes, int n_in,
                              void* d_out, int out_size, void* d_ws, size_t ws_size,
                              hipStream_t stream) {
    const int*   tok = (const int*)d_in[0];
    const int*   dep = (const int*)d_in[1];
    const float* vec = (const float*)d_in[2];
    const float* q   = (const float*)d_in[3];
    const float* W   = (const float*)d_in[4];
    const float* U   = (const float*)d_in[5];
    const float* D   = (const float*)d_in[6];
    const float* b   = (const float*)d_in[7];

    char* ws = (char*)d_ws;
    size_t off = 0;
    auto alloc = [&](size_t bytes) {
        void* p = ws + off;
        off += (bytes + 255) & ~(size_t)255;
        return p;
    };
    float* qD = (float*)alloc((size_t)QQ * 768 * 4);
    u16*   Wb = (u16*)alloc((size_t)768 * KEP * 2);
    u16*   Ub = (u16*)alloc((size_t)768 * HB * 2);
    u16*   vW = (u16*)alloc((size_t)VV * 768 * 2);
    u16*   h  = (u16*)alloc((size_t)BT * NND * HB * 2);
    u16*   g  = (u16*)alloc((size_t)BT * 64 * 768 * 2);
    if (ws_size < off) return;  // ~145 MiB needed; zero output signals ws too small

    k_prep<<<246, 256, 0, stream>>>(W, U, q, D, Wb, Ub, qD);

    // vW = (idx2vec @ W.T) as bf16, vocab-wide; A converted in-kernel
    k_gemmA<<<dim3(6, (VV + 127) / 128), 256, 0, stream>>>(vec, Wb, vW);

    k_leaf<<<BT * 64 / 4, 256, 0, stream>>>(tok, vW, qD, b, h);

    for (int lv = 1; lv <= 6; ++lv) {
        int pnl = 6 - lv;              // log2(parents per tree)
        int pn = 1 << pnl;
        int pstart = pn - 1;
        int cnl = pnl + 1;             // log2(children per tree)
        int cstart = (1 << cnl) - 1;
        int npT = BT * pn, ncT = BT * (1 << cnl);
        // g[children, 768] = h_child @ U.T  (A rows mapped into the tree layout)
        k_gemm<true><<<dim3(6, ncT / 128), 256, 0, stream>>>(
            h, Ub, g, ncT, 768, HB, cnl, cstart);
        k_update<<<npT / 4, 256, 0, stream>>>(tok, dep, vW, qD, b, g, h,
                                              (lv == 6) ? (float*)d_out : nullptr,
                                              pstart, pnl);
    }
}

// Round 10
// 208.638 us; speedup vs baseline: 1.3304x; 1.0617x over previous
//
#include <hip/hip_runtime.h>

typedef unsigned short u16;
typedef u16 u16x4 __attribute__((ext_vector_type(4)));
typedef u16 u16x8 __attribute__((ext_vector_type(8)));
typedef __bf16 bf16x8 __attribute__((ext_vector_type(8)));
typedef float f32x4 __attribute__((ext_vector_type(4)));

#define HB   256    // H
#define NND  127    // nodes per tree
#define BT   512    // trees (batch)
#define KE   300    // E
#define KEP  320    // E padded to 32-multiple
#define VV   50000  // vocab
#define QQ   10     // Q

#define AS1 __attribute__((address_space(1)))
#define AS3 __attribute__((address_space(3)))

__device__ __forceinline__ u16 f2bf(float f) {
    unsigned int u = __builtin_bit_cast(unsigned int, f);
    u += 0x7FFFu + ((u >> 16) & 1u);          // RNE
    return (u16)(u >> 16);
}
__device__ __forceinline__ float bf2f(u16 h) {
    unsigned int u = ((unsigned int)h) << 16;
    return __builtin_bit_cast(float, u);
}
__device__ __forceinline__ float sigm(float x) { return 1.f / (1.f + __expf(-x)); }

__device__ __forceinline__ void glds16(const u16* g, u16* l) {
    __builtin_amdgcn_global_load_lds((const AS1 void*)g, (AS3 void*)l, 16, 0, 0);
}

// ---------- vocab fp32 -> bf16 convert, coalesced: one u16x4 per thread ----------
// 300 % 4 == 0 -> every in-range chunk is a full aligned f32x4; c >= 300 chunks are pure pad.
__global__ __launch_bounds__(256) void k_conv(const float* __restrict__ src,
                                              u16* __restrict__ dst) {
    long i = (long)blockIdx.x * 256 + threadIdx.x;   // VV * 80 = 4,000,000 chunks
    int r = (int)(i / 80);
    int c = ((int)(i - (long)r * 80)) * 4;
    u16x4 o = {0, 0, 0, 0};
    if (c < KE) {
        f32x4 x = *(const f32x4*)(src + (long)r * KE + c);
#pragma unroll
        for (int e = 0; e < 4; ++e) o[e] = f2bf(x[e]);
    }
    *(u16x4*)(dst + i * 4) = o;
}

// ---------- merged prep: convert W (120 blks), U (96 blks), qD = q@D.T (30 blks) ----------
__global__ __launch_bounds__(256) void k_prep(const float* __restrict__ W,
                                              const float* __restrict__ U,
                                              const float* __restrict__ q,
                                              const float* __restrict__ D,
                                              u16* __restrict__ Wb,
                                              u16* __restrict__ Ub,
                                              float* __restrict__ qD) {
    int blk = blockIdx.x;
    if (blk < 120) {                       // W: 768 rows, K=300 -> Kp=320 (40 chunks)
        int i = blk * 256 + threadIdx.x;
        if (i < 768 * 40) {
            int r = i / 40, c = (i - r * 40) * 8;
            const float* s = W + (long)r * KE + c;
            u16x8 o;
#pragma unroll
            for (int e = 0; e < 8; ++e) o[e] = (c + e < KE) ? f2bf(s[e]) : (u16)0;
            *(u16x8*)(Wb + (long)i * 8) = o;
        }
    } else if (blk < 216) {                // U: 768 rows, K=Kp=256 (32 chunks)
        int i = (blk - 120) * 256 + threadIdx.x;
        if (i < 768 * 32) {
            int r = i / 32, c = (i - r * 32) * 8;
            const float* s = U + (long)r * HB + c;
            u16x8 o;
#pragma unroll
            for (int e = 0; e < 8; ++e) o[e] = f2bf(s[e]);
            *(u16x8*)(Ub + (long)i * 8) = o;
        }
    } else {                               // qD[i] over QQ*768
        int i = (blk - 216) * 256 + threadIdx.x;
        if (i < QQ * 768) {
            int qi = i / 768, col = i - qi * 768;
            const float* qr = q + qi * HB;
            const float* dr = D + col * HB;
            float s = 0.f;
            for (int k = 0; k < HB; ++k) s += qr[k] * dr[k];
            qD[i] = s;
        }
    }
}

// ---------- bf16 NT GEMM: global_load_lds(16B), 128x128 tile ----------
// Depth-3 pipeline, 4 LDS buffers, counted vmcnt (T4) — best measured variant (R6), frozen.
// C[M,N] = A[M,K] * B[N,K]^T ; A,B bf16 row-major, K/32 = nk >= 4, N % 128 == 0.
// optional A-row map: global_row = (r>>cnlog2)*127 + cstart + (r & ((1<<cnlog2)-1))
template <bool STORE_BF16>
__global__ __launch_bounds__(256) void k_gemm(const u16* __restrict__ A,
                                              const u16* __restrict__ B,
                                              void* __restrict__ C,
                                              int M, int N, int K,
                                              int map_cnlog2, int map_cstart) {
    __shared__ u16 As[4][128 * 32];
    __shared__ u16 Bs[4][128 * 32];

    // bijective XCD-chunked swizzle (m204) on linear bid, x-inner
    int nwg = gridDim.x * gridDim.y;
    int orig = blockIdx.y * gridDim.x + blockIdx.x;
    int qq = nwg >> 3, rr = nwg & 7;
    int xcd = orig & 7, cidx = orig >> 3;
    int wg = (xcd < rr ? xcd * (qq + 1) : rr * (qq + 1) + (xcd - rr) * qq) + cidx;
    int bx = wg % gridDim.x, by = wg / gridDim.x;
    int row0 = by * 128, col0 = bx * 128;

    int t = threadIdx.x, lane = t & 63, w = t >> 6;
    int wr = w >> 1, wc = w & 1;

    // staging geometry: per wave-issue, 64 lanes x 16B = 16 rows x 32 u16
    int cof = (lane & 3) * 8;            // u16 col offset
    int rin = lane >> 2;                 // 0..15 row within issue
    int ar0 = row0 + w * 32 + rin;
    int ar1 = ar0 + 16;
    auto mapfn = [&](int r) {
        if (r > M - 1) r = M - 1;
        if (map_cnlog2 >= 0) {
            int bt = r >> map_cnlog2;
            int of = r & ((1 << map_cnlog2) - 1);
            r = bt * NND + map_cstart + of;
        }
        return r;
    };
    const u16* aS0 = A + (long)mapfn(ar0) * K + cof;
    const u16* aS1 = A + (long)mapfn(ar1) * K + cof;
    const u16* bS0 = B + (long)(col0 + w * 32 + rin) * K + cof;
    const u16* bS1 = bS0 + 16L * K;
    int dof0 = (w * 32) * 32;
    int dof1 = (w * 32 + 16) * 32;

    f32x4 acc[4][4];
#pragma unroll
    for (int m = 0; m < 4; ++m)
#pragma unroll
        for (int n = 0; n < 4; ++n) acc[m][n] = f32x4{0.f, 0.f, 0.f, 0.f};

    int arl = wr * 64 + (lane & 15);
    int brl = wc * 64 + (lane & 15);
    int kk = (lane >> 4) * 8;

    auto stage = [&](int sel, int ko) {
        glds16(aS0 + ko, &As[sel][dof0]);
        glds16(aS1 + ko, &As[sel][dof1]);
        glds16(bS0 + ko, &Bs[sel][dof0]);
        glds16(bS1 + ko, &Bs[sel][dof1]);
    };
    auto compute = [&](int sel) {
        bf16x8 af[4], bfr[4];
#pragma unroll
        for (int m = 0; m < 4; ++m)
            af[m] = *(const bf16x8*)&As[sel][(arl + m * 16) * 32 + kk];
#pragma unroll
        for (int n = 0; n < 4; ++n)
            bfr[n] = *(const bf16x8*)&Bs[sel][(brl + n * 16) * 32 + kk];
#pragma unroll
        for (int m = 0; m < 4; ++m)
#pragma unroll
            for (int n = 0; n < 4; ++n)
                acc[m][n] = __builtin_amdgcn_mfma_f32_16x16x32_bf16(af[m], bfr[n], acc[m][n], 0, 0, 0);
    };

    int nk = K >> 5;                     // 8 or 10 here (>= 4 required)
    stage(0, 0); stage(1, 32); stage(2, 64);     // 12 loads/wave in flight
    for (int kt = 0; kt < nk - 3; ++kt) {
        asm volatile("s_waitcnt vmcnt(8)" ::: "memory");
        __builtin_amdgcn_s_barrier();
        __builtin_amdgcn_sched_barrier(0);
        compute(kt & 3);
        stage((kt + 3) & 3, (kt + 3) * 32);
    }
    asm volatile("s_waitcnt vmcnt(8)" ::: "memory");
    __builtin_amdgcn_s_barrier();
    __builtin_amdgcn_sched_barrier(0);
    compute((nk - 3) & 3);
    asm volatile("s_waitcnt vmcnt(4)" ::: "memory");
    __builtin_amdgcn_s_barrier();
    __builtin_amdgcn_sched_barrier(0);
    compute((nk - 2) & 3);
    asm volatile("s_waitcnt vmcnt(0)" ::: "memory");
    __builtin_amdgcn_s_barrier();
    __builtin_amdgcn_sched_barrier(0);
    compute((nk - 1) & 3);

    int crow = row0 + wr * 64 + (lane >> 4) * 4;
    int ccol = col0 + wc * 64 + (lane & 15);
#pragma unroll
    for (int m = 0; m < 4; ++m) {
#pragma unroll
        for (int n = 0; n < 4; ++n) {
#pragma unroll
            for (int j = 0; j < 4; ++j) {
                int r = crow + m * 16 + j;
                int c = ccol + n * 16;
                if (r < M) {
                    if (STORE_BF16) ((u16*)C)[(long)r * N + c] = f2bf(acc[m][n][j]);
                    else            ((float*)C)[(long)r * N + c] = acc[m][n][j];
                }
            }
        }
    }
}

// ---------- leaves, vectorized: one wave per leaf, 4 j per lane ----------
__global__ __launch_bounds__(256) void k_leaf(const int* __restrict__ tok,
                                              const u16* __restrict__ vW,
                                              const float* __restrict__ qD,
                                              const float* __restrict__ b,
                                              u16* __restrict__ h) {
    int w = threadIdx.x >> 6, t = threadIdx.x & 63;
    int leaf = blockIdx.x * 4 + w;             // 0..32767
    int j = t * 4;
    int bt = leaf >> 6, li = leaf & 63;        // 64 leaves per tree
    int row = bt * NND + 63 + li;
    long vwb = (long)tok[row] * 768;
    u16x4 vi = *(const u16x4*)(vW + vwb + 256 + j);
    u16x4 vu = *(const u16x4*)(vW + vwb + 512 + j);
    f32x4 qi = *(const f32x4*)(qD + 9 * 768 + 256 + j);
    f32x4 qu = *(const f32x4*)(qD + 9 * 768 + 512 + j);
    f32x4 bi = *(const f32x4*)(b + 256 + j);
    f32x4 bu = *(const f32x4*)(b + 512 + j);
    u16x4 o;
#pragma unroll
    for (int e = 0; e < 4; ++e) {
        float ii = bf2f(vi[e]) + qi[e] + bi[e];
        float uu = bf2f(vu[e]) + qu[e] + bu[e];
        o[e] = f2bf(tanhf(sigm(ii) * tanhf(uu)));
    }
    *(u16x4*)(h + (long)row * HB + j) = o;
}

// ---------- per-level update, vectorized: one wave per parent, 4 j per lane ----------
// g row layout per child c (compact level order): [0:256]=f-part, [256:512]=i, [512:768]=u
__global__ __launch_bounds__(256) void k_update(const int* __restrict__ tok,
                                                const int* __restrict__ dep,
                                                const u16* __restrict__ vW,
                                                const float* __restrict__ qD,
                                                const float* __restrict__ b,
                                                const u16* __restrict__ g,
                                                u16* __restrict__ h,
                                                float* __restrict__ out,
                                                int pstart, int pnl) {
    int w = threadIdx.x >> 6, t = threadIdx.x & 63;
    int pi = blockIdx.x * 4 + w;
    int j = t * 4;
    int bt = pi >> pnl, po = pi & ((1 << pnl) - 1);
    int pl = pstart + po;
    int gp  = bt * NND + pl;
    int gc1 = bt * NND + 2 * pl + 1, gc2 = gc1 + 1;
    long cc1 = (long)((bt << (pnl + 1)) + 2 * po) * 768;  // g rows of the two children
    long cc2 = cc1 + 768;
    long vwb = (long)tok[gp] * 768;
    int d1 = dep[gc1] * 768, d2 = dep[gc2] * 768;
    u16x4 vf  = *(const u16x4*)(vW + vwb + j);
    u16x4 vi  = *(const u16x4*)(vW + vwb + 256 + j);
    u16x4 vu  = *(const u16x4*)(vW + vwb + 512 + j);
    u16x4 gf1 = *(const u16x4*)(g + cc1 + j);
    u16x4 gf2 = *(const u16x4*)(g + cc2 + j);
    u16x4 gi1 = *(const u16x4*)(g + cc1 + 256 + j);
    u16x4 gi2 = *(const u16x4*)(g + cc2 + 256 + j);
    u16x4 gu1 = *(const u16x4*)(g + cc1 + 512 + j);
    u16x4 gu2 = *(const u16x4*)(g + cc2 + 512 + j);
    f32x4 qf1 = *(const f32x4*)(qD + d1 + j);
    f32x4 qf2 = *(const f32x4*)(qD + d2 + j);
    f32x4 qi1 = *(const f32x4*)(qD + d1 + 256 + j);
    f32x4 qi2 = *(const f32x4*)(qD + d2 + 256 + j);
    f32x4 qu1 = *(const f32x4*)(qD + d1 + 512 + j);
    f32x4 qu2 = *(const f32x4*)(qD + d2 + 512 + j);
    f32x4 bf_ = *(const f32x4*)(b + j);
    f32x4 bi_ = *(const f32x4*)(b + 256 + j);
    f32x4 bu_ = *(const f32x4*)(b + 512 + j);
    u16x4 h1v = *(const u16x4*)(h + (long)gc1 * HB + j);
    u16x4 h2v = *(const u16x4*)(h + (long)gc2 * HB + j);
    f32x4 res;
    u16x4 resb;
#pragma unroll
    for (int e = 0; e < 4; ++e) {
        float xf = bf2f(vf[e]) + bf_[e];
        float f1 = sigm(xf + bf2f(gf1[e]) + qf1[e]);
        float f2 = sigm(xf + bf2f(gf2[e]) + qf2[e]);
        float ii = bf2f(vi[e]) + bf2f(gi1[e]) + bf2f(gi2[e]) + qi1[e] + qi2[e] + bi_[e];
        float uu = bf2f(vu[e]) + bf2f(gu1[e]) + bf2f(gu2[e]) + qu1[e] + qu2[e] + bu_[e];
        float hn = tanhf(sigm(ii) * tanhf(uu) + f1 * bf2f(h1v[e]) + f2 * bf2f(h2v[e]));
        res[e] = hn;
        resb[e] = f2bf(hn);
    }
    if (out) *(f32x4*)(out + (long)pi * HB + j) = res;     // lv6: pi == bt, fp32 output
    else     *(u16x4*)(h + (long)gp * HB + j) = resb;
}

extern "C" void kernel_launch(void* const* d_in, const int* in_sizes, int n_in,
                              void* d_out, int out_size, void* d_ws, size_t ws_size,
                              hipStream_t stream) {
    const int*   tok = (const int*)d_in[0];
    const int*   dep = (const int*)d_in[1];
    const float* vec = (const float*)d_in[2];
    const float* q   = (const float*)d_in[3];
    const float* W   = (const float*)d_in[4];
    const float* U   = (const float*)d_in[5];
    const float* D   = (const float*)d_in[6];
    const float* b   = (const float*)d_in[7];

    char* ws = (char*)d_ws;
    size_t off = 0;
    auto alloc = [&](size_t bytes) {
        void* p = ws + off;
        off += (bytes + 255) & ~(size_t)255;
        return p;
    };
    float* qD = (float*)alloc((size_t)QQ * 768 * 4);
    u16*   vb = (u16*)alloc((size_t)VV * KEP * 2);
    u16*   Wb = (u16*)alloc((size_t)768 * KEP * 2);
    u16*   Ub = (u16*)alloc((size_t)768 * HB * 2);
    u16*   vW = (u16*)alloc((size_t)VV * 768 * 2);
    u16*   h  = (u16*)alloc((size_t)BT * NND * HB * 2);
    u16*   g  = (u16*)alloc((size_t)BT * 64 * 768 * 2);
    if (ws_size < off) return;  // ~177 MiB needed; zero output signals ws too small

    k_conv<<<(VV * 80) / 256, 256, 0, stream>>>(vec, vb);
    k_prep<<<246, 256, 0, stream>>>(W, U, q, D, Wb, Ub, qD);

    // vW = (idx2vec @ W.T) as bf16, vocab-wide
    k_gemm<true><<<dim3(6, (VV + 127) / 128), 256, 0, stream>>>(
        vb, Wb, vW, VV, 768, KEP, -1, 0);

    k_leaf<<<BT * 64 / 4, 256, 0, stream>>>(tok, vW, qD, b, h);

    for (int lv = 1; lv <= 6; ++lv) {
        int pnl = 6 - lv;              // log2(parents per tree)
        int pn = 1 << pnl;
        int pstart = pn - 1;
        int cnl = pnl + 1;             // log2(children per tree)
        int cstart = (1 << cnl) - 1;
        int npT = BT * pn, ncT = BT * (1 << cnl);
        // g[children, 768] = h_child @ U.T  (A rows mapped into the tree layout)
        k_gemm<true><<<dim3(6, ncT / 128), 256, 0, stream>>>(
            h, Ub, g, ncT, 768, HB, cnl, cstart);
        k_update<<<npT / 4, 256, 0, stream>>>(tok, dep, vW, qD, b, g, h,
                                              (lv == 6) ? (float*)d_out : nullptr,
                                              pstart, pnl);
    }
}